// Round 8
// baseline (398.204 us; speedup 1.0000x reference)
//
#include <hip/hip_runtime.h>
#include <hip/hip_cooperative_groups.h>
#include <math.h>

namespace cg = cooperative_groups;

// Problem constants (from reference setup_inputs)
constexpr int B   = 32;
constexpr int C   = 256;
constexpr int HW  = 56 * 56;       // 3136
constexpr int HW4 = HW / 4;        // 784 float4 per (b,c) plane
constexpr int HID = 32;            // C / R, R=8
constexpr float LAMBDA_ALPHA = 1.0f;
constexpr float LAMBDA_BETA  = 0.5f;
constexpr int BDIM = 256;
constexpr int GRID = 1024;                 // 4 blocks/CU on 256 CUs — co-resident
constexpr int PPB  = (B * C) / GRID;       // 8 planes per block

// ---------------------------------------------------------------------------
// Single cooperative kernel:
//   Phase A: per-(b,c) mean over HW (each block: 8 contiguous planes)
//   Phase B: fc1 GEMV on blocks 0..31 (one batch row each)
//   Phase C: per-plane coefficients (32 threads, dot-32 each) + streaming apply
// ---------------------------------------------------------------------------
__global__ __launch_bounds__(BDIM, 4) void fused_kernel(
    const float* __restrict__ x,
    const float* __restrict__ fc1_w, const float* __restrict__ fc1_b,
    const float* __restrict__ fc2_w, const float* __restrict__ fc2_b,
    float* __restrict__ out,
    float* __restrict__ pooled,      // d_ws: B*C floats
    float* __restrict__ h)           // d_ws: B*HID floats
{
    cg::grid_group grid = cg::this_grid();
    const int tid  = threadIdx.x;
    const int lane = tid & 63;
    const int wid  = tid >> 6;
    const int base = blockIdx.x * PPB;

    __shared__ float wsum[BDIM / 64];
    __shared__ float scoef[PPB][4];

    // ---- Phase A: pool -------------------------------------------------
    for (int i = 0; i < PPB; ++i) {
        const int bc = base + i;
        const float4* x4 = reinterpret_cast<const float4*>(x) + (size_t)bc * HW4;
        float s = 0.0f;
        for (int t = tid; t < HW4; t += BDIM) {
            float4 v = x4[t];
            s += (v.x + v.y) + (v.z + v.w);
        }
        for (int off = 32; off > 0; off >>= 1) s += __shfl_down(s, off, 64);
        if (lane == 0) wsum[wid] = s;
        __syncthreads();
        if (tid == 0)
            pooled[bc] = (wsum[0] + wsum[1] + wsum[2] + wsum[3]) * (1.0f / (float)HW);
        __syncthreads();                     // wsum reused next iteration
    }

    grid.sync();

    // ---- Phase B: fc1 (blocks 0..31, b = blockIdx.x) --------------------
    if (blockIdx.x < B) {
        const int b  = blockIdx.x;
        const int hh = tid >> 3;             // 32 hidden units
        const int sub = tid & 7;             // 8 lanes per unit
        const float* pp = pooled + b * C;
        const float* pw = fc1_w + hh * C;
        float acc = 0.0f;
        #pragma unroll
        for (int q = 0; q < C / 8; ++q) {
            const int c = sub * (C / 8) + q;
            acc = fmaf(pp[c], pw[c], acc);
        }
        // sum 8 consecutive lanes (same 64-lane wave)
        acc += __shfl_down(acc, 4, 64);
        acc += __shfl_down(acc, 2, 64);
        acc += __shfl_down(acc, 1, 64);
        if (sub == 0) h[b * HID + hh] = fmaxf(acc + fc1_b[hh], 0.0f);
    }

    grid.sync();

    // ---- Phase C: coefficients into LDS, then apply ---------------------
    if (tid < PPB * 4) {
        const int i   = tid >> 2;            // plane within block
        const int idx = tid & 3;             // 0:a0 1:b0 2:a1 3:b1
        const int bc  = base + i;
        const int b   = bc >> 8;
        const int c   = bc & (C - 1);
        const int k   = idx >> 1;
        const int e   = idx & 1;
        const int o   = 2 * c + e;
        const float* w2 = fc2_w + (size_t)(k * 2 * C + o) * HID;
        const float* hp = h + b * HID;
        float acc = fc2_b[k * 2 * C + o];
        #pragma unroll
        for (int q = 0; q < HID; ++q) acc = fmaf(w2[q], hp[q], acc);
        const float d = 2.0f / (1.0f + expf(-acc)) - 1.0f;
        scoef[i][idx] = ((k == 0) ? 1.0f : 0.0f) +
                        ((e == 0) ? LAMBDA_ALPHA : LAMBDA_BETA) * d;
    }
    __syncthreads();

    for (int i = 0; i < PPB; ++i) {
        const int bc = base + i;
        const float a0 = scoef[i][0], b0 = scoef[i][1];
        const float a1 = scoef[i][2], b1 = scoef[i][3];
        const float4* x4 = reinterpret_cast<const float4*>(x) + (size_t)bc * HW4;
        float4*       o4 = reinterpret_cast<float4*>(out) + (size_t)bc * HW4;
        for (int t = tid; t < HW4; t += BDIM) {
            float4 v = x4[t];
            float4 r;
            r.x = fmaxf(fmaf(v.x, a0, b0), fmaf(v.x, a1, b1));
            r.y = fmaxf(fmaf(v.y, a0, b0), fmaf(v.y, a1, b1));
            r.z = fmaxf(fmaf(v.z, a0, b0), fmaf(v.z, a1, b1));
            r.w = fmaxf(fmaf(v.w, a0, b0), fmaf(v.w, a1, b1));
            o4[t] = r;
        }
    }
}

// ---------------------------------------------------------------------------
extern "C" void kernel_launch(void* const* d_in, const int* in_sizes, int n_in,
                              void* d_out, int out_size, void* d_ws, size_t ws_size,
                              hipStream_t stream) {
    const float* x     = (const float*)d_in[0];
    const float* fc1_w = (const float*)d_in[1];
    const float* fc1_b = (const float*)d_in[2];
    const float* fc2_w = (const float*)d_in[3];
    const float* fc2_b = (const float*)d_in[4];
    float* out = (float*)d_out;

    // workspace: pooled (B*C floats) | h (B*HID floats)
    float* pooled = (float*)d_ws;
    float* h      = pooled + (size_t)B * C;

    void* args[] = { (void*)&x, (void*)&fc1_w, (void*)&fc1_b, (void*)&fc2_w,
                     (void*)&fc2_b, (void*)&out, (void*)&pooled, (void*)&h };
    hipLaunchCooperativeKernel((void*)fused_kernel, dim3(GRID), dim3(BDIM),
                               args, 0, stream);
}

// Round 11
// 205.656 us; speedup vs baseline: 1.9363x; 1.9363x over previous
//
#include <hip/hip_runtime.h>
#include <math.h>

// Problem constants (from reference setup_inputs)
constexpr int B   = 32;
constexpr int C   = 256;
constexpr int HW  = 56 * 56;       // 3136
constexpr int HW4 = HW / 4;        // 784 float4 per (b,c) plane
constexpr int HID = 32;            // C / R, R=8
constexpr float LAMBDA_ALPHA = 1.0f;
constexpr float LAMBDA_BETA  = 0.5f;
constexpr int BDIM = 256;
constexpr int WPB  = BDIM / 64;            // 4 waves per block, one plane per wave
constexpr int FULL = HW4 / 64;             // 12 full rounds of 64 lanes
constexpr int TAIL = HW4 - FULL * 64;      // 16 remaining float4

// ---------------------------------------------------------------------------
// Kernel 1: pool — one WAVE per (b,c) plane.  12 unrolled independent float4
// loads per lane, wave-internal shuffle reduce, zero barriers.
// grid = B*C/WPB = 2048 blocks.
// ---------------------------------------------------------------------------
__global__ __launch_bounds__(BDIM) void pool_kernel(const float* __restrict__ x,
                                                    float* __restrict__ pooled) {
    const int lane = threadIdx.x & 63;
    const int wid  = threadIdx.x >> 6;
    const int bc   = blockIdx.x * WPB + wid;         // 0 .. 8191
    const float4* x4 = reinterpret_cast<const float4*>(x) + (size_t)bc * HW4;

    float s = 0.0f;
    #pragma unroll
    for (int r = 0; r < FULL; ++r) {
        float4 v = x4[r * 64 + lane];
        s += (v.x + v.y) + (v.z + v.w);
    }
    if (lane < TAIL) {
        float4 v = x4[FULL * 64 + lane];
        s += (v.x + v.y) + (v.z + v.w);
    }
    for (int off = 32; off > 0; off >>= 1) s += __shfl_down(s, off, 64);
    if (lane == 0) pooled[bc] = s * (1.0f / (float)HW);
}

// ---------------------------------------------------------------------------
// Kernel 2: fc1 — one block per batch row b.
// h[b,hh] = relu(pooled[b,:] . fc1_w[hh,:] + fc1_b[hh]); 32 units x 8 lanes.
// ---------------------------------------------------------------------------
__global__ __launch_bounds__(BDIM) void fc1_kernel(const float* __restrict__ pooled,
                                                   const float* __restrict__ fc1_w,
                                                   const float* __restrict__ fc1_b,
                                                   float* __restrict__ h) {
    const int b   = blockIdx.x;
    const int tid = threadIdx.x;
    const int hh  = tid >> 3;                        // 32 hidden units
    const int sub = tid & 7;                         // 8 lanes per unit
    const float* pp = pooled + b * C;
    const float* pw = fc1_w + hh * C;
    float acc = 0.0f;
    #pragma unroll
    for (int q = 0; q < C / 8; ++q) {
        const int c = sub * (C / 8) + q;
        acc = fmaf(pp[c], pw[c], acc);
    }
    // sum 8 consecutive lanes (aligned groups within one 64-lane wave)
    acc += __shfl_down(acc, 4, 64);
    acc += __shfl_down(acc, 2, 64);
    acc += __shfl_down(acc, 1, 64);
    if (sub == 0) h[b * HID + hh] = fmaxf(acc + fc1_b[hh], 0.0f);
}

// ---------------------------------------------------------------------------
// Kernel 3: fused coef + apply — one WAVE per plane, zero barriers.
// Coefficients: 4 dot-32 over fc2_w (uniform, scalar-cached) + 4 sigmoids,
// computed redundantly per lane.  Then a 12-round unrolled stream.
// ---------------------------------------------------------------------------
__global__ __launch_bounds__(BDIM) void apply_kernel(const float* __restrict__ x,
                                                     const float* __restrict__ h,
                                                     const float* __restrict__ fc2_w,
                                                     const float* __restrict__ fc2_b,
                                                     float* __restrict__ out) {
    const int lane = threadIdx.x & 63;
    const int wid  = threadIdx.x >> 6;
    const int bc   = blockIdx.x * WPB + wid;         // 0 .. 8191
    const int b    = bc >> 8;                        // / C
    const int c    = bc & (C - 1);
    const float* hp = h + b * HID;

    float cf[4];                                     // a0, b0, a1, b1
    #pragma unroll
    for (int k = 0; k < 2; ++k) {
        #pragma unroll
        for (int e = 0; e < 2; ++e) {
            const int o = 2 * c + e;
            const float* w2 = fc2_w + (size_t)(k * 2 * C + o) * HID;
            float acc = fc2_b[k * 2 * C + o];
            #pragma unroll
            for (int q = 0; q < HID; ++q) acc = fmaf(w2[q], hp[q], acc);
            const float d = 2.0f / (1.0f + expf(-acc)) - 1.0f;
            cf[k * 2 + e] = ((k == 0) ? 1.0f : 0.0f) +
                            ((e == 0) ? LAMBDA_ALPHA : LAMBDA_BETA) * d;
        }
    }

    const float4* x4 = reinterpret_cast<const float4*>(x) + (size_t)bc * HW4;
    float4*       o4 = reinterpret_cast<float4*>(out) + (size_t)bc * HW4;
    #pragma unroll
    for (int r = 0; r < FULL; ++r) {
        float4 v = x4[r * 64 + lane];
        float4 rr;
        rr.x = fmaxf(fmaf(v.x, cf[0], cf[1]), fmaf(v.x, cf[2], cf[3]));
        rr.y = fmaxf(fmaf(v.y, cf[0], cf[1]), fmaf(v.y, cf[2], cf[3]));
        rr.z = fmaxf(fmaf(v.z, cf[0], cf[1]), fmaf(v.z, cf[2], cf[3]));
        rr.w = fmaxf(fmaf(v.w, cf[0], cf[1]), fmaf(v.w, cf[2], cf[3]));
        o4[r * 64 + lane] = rr;
    }
    if (lane < TAIL) {
        float4 v = x4[FULL * 64 + lane];
        float4 rr;
        rr.x = fmaxf(fmaf(v.x, cf[0], cf[1]), fmaf(v.x, cf[2], cf[3]));
        rr.y = fmaxf(fmaf(v.y, cf[0], cf[1]), fmaf(v.y, cf[2], cf[3]));
        rr.z = fmaxf(fmaf(v.z, cf[0], cf[1]), fmaf(v.z, cf[2], cf[3]));
        rr.w = fmaxf(fmaf(v.w, cf[0], cf[1]), fmaf(v.w, cf[2], cf[3]));
        o4[FULL * 64 + lane] = rr;
    }
}

// ---------------------------------------------------------------------------
extern "C" void kernel_launch(void* const* d_in, const int* in_sizes, int n_in,
                              void* d_out, int out_size, void* d_ws, size_t ws_size,
                              hipStream_t stream) {
    const float* x     = (const float*)d_in[0];
    const float* fc1_w = (const float*)d_in[1];
    const float* fc1_b = (const float*)d_in[2];
    const float* fc2_w = (const float*)d_in[3];
    const float* fc2_b = (const float*)d_in[4];
    float* out = (float*)d_out;

    // workspace: pooled (B*C floats) | h (B*HID floats)
    float* pooled = (float*)d_ws;
    float* h      = pooled + (size_t)B * C;

    pool_kernel<<<(B * C) / WPB, BDIM, 0, stream>>>(x, pooled);
    fc1_kernel<<<B, BDIM, 0, stream>>>(pooled, fc1_w, fc1_b, h);
    apply_kernel<<<(B * C) / WPB, BDIM, 0, stream>>>(x, h, fc2_w, fc2_b, out);
}